// Round 8
// baseline (661.851 us; speedup 1.0000x reference)
//
#include <hip/hip_runtime.h>
#include <stdint.h>

#define TT 2048
#define DD 256
#define KK 1024
#define BB 16
#define NQ (BB*TT)   // 32768 queries per tensor

typedef __attribute__((ext_vector_type(8))) short short8;
typedef __attribute__((ext_vector_type(4))) short s16x4;
typedef __attribute__((ext_vector_type(4))) float f32x4;

#define AS1 __attribute__((address_space(1)))
#define AS3 __attribute__((address_space(3)))

__device__ __forceinline__ short bf16_rn(float x){
  unsigned u = __builtin_bit_cast(unsigned, x);
  unsigned r = u + 0x7fffu + ((u >> 16) & 1u);   // round-to-nearest-even
  return (short)(r >> 16);
}
__device__ __forceinline__ float bf16_to_f(short h){
  unsigned u = ((unsigned)(unsigned short)h) << 16;
  return __builtin_bit_cast(float, u);
}

// ---------------------------------------------------------------------------
// k1: codebook prep (unchanged from r5, verified): bf16 hi/lo split in the
// MFMA-A frag swizzle (per (ct,s) tile: 64 lanes x 16B contiguous), |e|^2,
// zero counts/loss.  pos = ((ct*8+s)*64 + q*16 + c)*8 + j ; code k = ct*16+c.
// ---------------------------------------------------------------------------
__global__ void vq_prep(const float* __restrict__ cb_top,
                        const float* __restrict__ cb_bot,
                        short* __restrict__ ws_cb,
                        float* __restrict__ e2_all,
                        int* __restrict__ counts,
                        float* __restrict__ loss_acc){
  int gid = blockIdx.x*256 + threadIdx.x;          // 512 blocks = 2048 waves
  int wv = gid >> 6, lane = gid & 63;
  int t = wv >> 10, k = wv & 1023;
  const float* row = (t ? cb_bot : cb_top) + (size_t)k*DD;
  f32x4 v = *(const f32x4*)(row + lane*4);
  float s2 = v[0]*v[0] + v[1]*v[1] + v[2]*v[2] + v[3]*v[3];
  #pragma unroll
  for (int off = 1; off < 64; off <<= 1) s2 += __shfl_xor(s2, off, 64);
  if (lane == 0) e2_all[t*KK + k] = s2;

  s16x4 hi4, lo4;
  #pragma unroll
  for (int e = 0; e < 4; ++e){
    short hi = bf16_rn(v[e]);
    hi4[e] = hi;
    lo4[e] = bf16_rn(v[e] - bf16_to_f(hi));
  }
  int d0 = lane*4;
  int ct = k >> 4, c = k & 15, s = d0 >> 5, q = (d0 >> 3) & 3, j = d0 & 7;
  size_t pos = ((size_t)(ct*8 + s)*64 + q*16 + c)*8 + j;
  short* hib = ws_cb + (size_t)t * (2*KK*DD);
  *(s16x4*)(hib + pos) = hi4;
  *(s16x4*)(hib + (size_t)KK*DD + pos) = lo4;

  if (gid < 2*KK) counts[gid] = 0;
  if (gid < 2)    loss_acc[gid] = 0.f;
}

// ---------------------------------------------------------------------------
// k2: h prep. Split h into bf16 hi/lo planes in the MFMA-B frag swizzle:
// plane offset ((qt*8+s)*64 + lane)*8 + j holds X[d = s*32+(lane>>4)*8+j]
// [q = qt*16 + (lane&15)]  (bitwise-identical split to the old in-kernel
// prologue). Also accumulates Sum|x|^2 straight into loss_acc (so vq_main
// only adds Sum best).  ws_h lives in d_out (64 MB, exactly the z region,
// overwritten later by vq_zgather).
// ---------------------------------------------------------------------------
__global__ void vq_prep_h(const float* __restrict__ h_top,
                          const float* __restrict__ h_bot,
                          short* __restrict__ ws_h,
                          float* __restrict__ loss_acc){
  int gid = blockIdx.x*256 + threadIdx.x;          // 8192 blocks = 2M threads
  int tz = gid >> 20;
  int rem = gid & ((1<<20)-1);
  int qt = rem >> 9, s = (rem >> 6) & 7, lane = rem & 63;
  int q = qt*16 + (lane & 15);
  int b = q >> 11, ti = q & (TT-1);
  int d0 = s*32 + (lane>>4)*8;
  const float* hp = (tz ? h_bot : h_top) + ((size_t)b*DD + d0)*TT + ti;
  short8 h8, l8; float x2p = 0.f;
  #pragma unroll
  for (int j = 0; j < 8; ++j){
    float v = hp[(size_t)j*TT];
    x2p += v*v;
    short hi = bf16_rn(v);
    h8[j] = hi;
    l8[j] = bf16_rn(v - bf16_to_f(hi));
  }
  short* dst = ws_h + (size_t)tz*(2*(size_t)NQ*DD) + ((size_t)(qt*8+s)*64 + lane)*8;
  *(short8*)dst = h8;
  *(short8*)(dst + (size_t)NQ*DD) = l8;
  #pragma unroll
  for (int o = 1; o < 64; o <<= 1) x2p += __shfl_xor(x2p, o, 64);
  if (lane == 0) atomicAdd(&loss_acc[tz], x2p);
}

// ---------------------------------------------------------------------------
// k3: tiled GEMM argmin. grid (256,2) = 512 WGs (2/CU), block 256 = 4 waves.
// WG tile: 128 queries x 128-code M-tile; wave (wm,wn) owns 64x64; M-loop
// over 8 code-tiles x 8 K-steps = 64 iters. Per iter: stage A 16KB + B 16KB
// (global_load_lds w=16), 16 ds_read_b128/wave, 48 MFMA into 16 INDEPENDENT
// acc chains (kills r3's 24-deep single-chain: MfmaUtil said pipe was
// dep-latency-stalled 77%). Operands stream from LDS -> no giant per-thread
// frag arrays -> no spill (the r0/r1/r5/r7 poison).
// __launch_bounds__(256,1): natural VGPR (r6 proven). LDS 69 KB -> 2 WGs/CU.
// No z write here: idx only (epilogue split into vq_zgather).
// ---------------------------------------------------------------------------
__global__ __launch_bounds__(256, 1) void vq_main(
    const short* __restrict__ ws_cb, const short* __restrict__ ws_h,
    const float* __restrict__ e2_all,
    int* __restrict__ idx_all, int* __restrict__ counts,
    float* __restrict__ loss_acc)
{
  const int tz = blockIdx.y;
  const short* cbA = ws_cb + (size_t)tz*(2*KK*DD);           // hi; lo at +KK*DD
  const short* hB  = ws_h  + (size_t)tz*(2*(size_t)NQ*DD);   // hi; lo at +NQ*DD
  const float* e2  = e2_all + tz*KK;

  const int tid = threadIdx.x;
  const int w = tid >> 6, lane = tid & 63;
  const int wm = w >> 1, wn = w & 1;
  const int q0 = blockIdx.x*128;
  const int qt0 = q0 >> 4;

  __shared__ short aL[2][2][8][512];   // [buf][hl][ct_l][lane*8+j]  32 KiB
  __shared__ short bL[2][2][8][512];   // [buf][hl][qt_l][lane*8+j]  32 KiB
  __shared__ float e2s[KK];            // 4 KiB
  __shared__ float smv[128];
  __shared__ int   smi[128];           // 69 KiB total

  // e2 -> LDS (drained by first __syncthreads)
  *(f32x4*)(e2s + tid*4) = *(const f32x4*)(e2 + tid*4);

  // cooperative stage of iteration it into buf: A units u<16, B units u>=16
  auto stage = [&](int buf, int it){
    const int mt = it >> 3, ks = it & 7;
    short* aBase = &aL[buf][0][0][0];
    short* bBase = &bL[buf][0][0][0];
    #pragma unroll
    for (int k2 = 0; k2 < 8; ++k2){
      int u = w*8 + k2;
      if (u < 16){
        int hl = u & 1, ct_l = u >> 1;
        const short* src = cbA + (size_t)hl*(KK*DD)
                         + (size_t)((mt*8 + ct_l)*8 + ks)*512 + lane*8;
        short* dst = aBase + (hl*8 + ct_l)*512 + lane*8;
        __builtin_amdgcn_global_load_lds((AS1 void*)src, (AS3 void*)dst, 16, 0, 0);
      } else {
        int v2 = u - 16, hl = v2 & 1, qt_l = v2 >> 1;
        const short* src = hB + (size_t)hl*((size_t)NQ*DD)
                         + (size_t)((qt0 + qt_l)*8 + ks)*512 + lane*8;
        short* dst = bBase + (hl*8 + qt_l)*512 + lane*8;
        __builtin_amdgcn_global_load_lds((AS1 void*)src, (AS3 void*)dst, 16, 0, 0);
      }
    }
  };

  stage(0, 0);

  f32x4 acc[4][4];
  #pragma unroll
  for (int am = 0; am < 4; ++am)
    #pragma unroll
    for (int bn = 0; bn < 4; ++bn)
      acc[am][bn] = (f32x4){0.f,0.f,0.f,0.f};

  float best[4] = {3.4e38f, 3.4e38f, 3.4e38f, 3.4e38f};
  int   bidx[4] = {0,0,0,0};

  for (int it = 0; it < 64; ++it){
    const int buf = it & 1;
    const int mt = it >> 3, ks = it & 7;
    __syncthreads();                              // stage(it) landed; buf^1 free
    if (it + 1 < 64) stage(buf ^ 1, it + 1);
    __builtin_amdgcn_sched_barrier(0);            // stage issues before reads

    short8 ah[4], al4[4], bh[4], bl4[4];
    #pragma unroll
    for (int am = 0; am < 4; ++am){
      ah[am]  = *(const short8*)(&aL[buf][0][wm*4+am][lane*8]);
      al4[am] = *(const short8*)(&aL[buf][1][wm*4+am][lane*8]);
    }
    #pragma unroll
    for (int bn = 0; bn < 4; ++bn){
      bh[bn]  = *(const short8*)(&bL[buf][0][wn*4+bn][lane*8]);
      bl4[bn] = *(const short8*)(&bL[buf][1][wn*4+bn][lane*8]);
    }
    __builtin_amdgcn_s_setprio(1);
    #pragma unroll
    for (int am = 0; am < 4; ++am)
      #pragma unroll
      for (int bn = 0; bn < 4; ++bn){
        acc[am][bn] = __builtin_amdgcn_mfma_f32_16x16x32_bf16(ah[am],  bh[bn],  acc[am][bn], 0,0,0);
        acc[am][bn] = __builtin_amdgcn_mfma_f32_16x16x32_bf16(ah[am],  bl4[bn], acc[am][bn], 0,0,0);
        acc[am][bn] = __builtin_amdgcn_mfma_f32_16x16x32_bf16(al4[am], bh[bn],  acc[am][bn], 0,0,0);
      }
    __builtin_amdgcn_s_setprio(0);

    if (ks == 7){                                 // M-tile argmin + acc reset
      const int g4 = lane >> 4;
      #pragma unroll
      for (int am = 0; am < 4; ++am){
        const int code0 = mt*128 + wm*64 + am*16 + g4*4;
        const f32x4 e2v = *(const f32x4*)(e2s + code0);
        #pragma unroll
        for (int bn = 0; bn < 4; ++bn){
          #pragma unroll
          for (int r = 0; r < 4; ++r){
            float sv = e2v[r] - 2.0f*acc[am][bn][r];
            if (sv < best[bn]){ best[bn] = sv; bidx[bn] = code0 + r; }
          }
          acc[am][bn] = (f32x4){0.f,0.f,0.f,0.f};
        }
      }
    }
  }

  // cross-lane-group reduce (code rows are quad-partitioned across lane>>4)
  #pragma unroll
  for (int o = 16; o <= 32; o <<= 1){
    #pragma unroll
    for (int bn = 0; bn < 4; ++bn){
      float ov = __shfl_xor(best[bn], o, 64);
      int   oi = __shfl_xor(bidx[bn], o, 64);
      if (ov < best[bn] || (ov == best[bn] && oi < bidx[bn])){ best[bn] = ov; bidx[bn] = oi; }
    }
  }

  // lane l handles q_local = wn*64 + l  (bn = l>>4, col = l&15)
  const int g4 = lane >> 4;
  float bv = (g4 == 0) ? best[0] : (g4 == 1) ? best[1] : (g4 == 2) ? best[2] : best[3];
  int   bi = (g4 == 0) ? bidx[0] : (g4 == 1) ? bidx[1] : (g4 == 2) ? bidx[2] : bidx[3];

  __syncthreads();
  if (wm == 1){ smv[wn*64 + lane] = bv; smi[wn*64 + lane] = bi; }
  __syncthreads();
  if (wm == 0){
    float ov = smv[wn*64 + lane]; int oi = smi[wn*64 + lane];
    if (ov < bv || (ov == bv && oi < bi)){ bv = ov; bi = oi; }
    idx_all[tz*NQ + q0 + wn*64 + lane] = bi;
    atomicAdd(&counts[tz*KK + bi], 1);
    float ld = bv;                                 // Sum|x|^2 added by k2
    #pragma unroll
    for (int o = 1; o < 64; o <<= 1) ld += __shfl_xor(ld, o, 64);
    if (lane == 0) atomicAdd(&loss_acc[tz], ld);
  }
}

// ---------------------------------------------------------------------------
// k4: z gather. Thread = (tz, quarter of D, q). Stores are 64-lane contiguous
// (consecutive q -> consecutive t). Reads are codebook-row gathers (L2-hit).
// Overwrites the ws_h scratch region of d_out with the real z output.
// ---------------------------------------------------------------------------
__global__ void vq_zgather(const float* __restrict__ cb_top,
                           const float* __restrict__ cb_bot,
                           const int* __restrict__ idx_all,
                           float* __restrict__ out){
  int gid = blockIdx.x*256 + threadIdx.x;          // 1024 blocks = 262144 thr
  int tz = gid >> 17;
  int rem = gid & ((1<<17)-1);
  int quarter = rem >> 15;
  int q = rem & (NQ-1);
  int b = q >> 11, ti = q & (TT-1);
  int idx = idx_all[tz*NQ + q];
  const float* crow = (tz ? cb_bot : cb_top) + (size_t)idx*DD + quarter*64;
  float* zb = out + (size_t)tz*((size_t)NQ*DD) + (size_t)(b*DD + quarter*64)*TT + ti;
  #pragma unroll
  for (int d = 0; d < 64; d += 4){
    f32x4 cv = *(const f32x4*)(crow + d);
    zb[(size_t)(d+0)*TT] = cv[0];
    zb[(size_t)(d+1)*TT] = cv[1];
    zb[(size_t)(d+2)*TT] = cv[2];
    zb[(size_t)(d+3)*TT] = cv[3];
  }
}

// ---------------------------------------------------------------------------
// k5: perplexities + loss scalars. outs = d_out + 2*NQ*DD.
// ---------------------------------------------------------------------------
__global__ void vq_final(const int* __restrict__ counts,
                         const float* __restrict__ loss_acc,
                         float* __restrict__ outs){
  __shared__ float red[1024];
  const int tid = threadIdx.x;
  const int t = blockIdx.x;
  float p = (float)counts[t*KK + tid] * (1.0f/(float)NQ);
  red[tid] = p * logf(p + 1e-10f);
  __syncthreads();
  for (int s = 512; s > 0; s >>= 1){
    if (tid < s) red[tid] += red[tid + s];
    __syncthreads();
  }
  if (tid == 0) outs[2 + t] = expf(-red[0]);
  if (t == 0 && tid == 0){
    float l = (loss_acc[0] + loss_acc[1]) * (1.0f/8388608.0f);
    outs[0] = l;   // vq_loss
    outs[1] = l;   // commitment_loss (same forward value)
  }
}

extern "C" void kernel_launch(void* const* d_in, const int* in_sizes, int n_in,
                              void* d_out, int out_size, void* d_ws, size_t ws_size,
                              hipStream_t stream)
{
  (void)in_sizes; (void)n_in; (void)out_size; (void)ws_size;
  const float* h_top  = (const float*)d_in[0];
  const float* h_bot  = (const float*)d_in[1];
  const float* cb_top = (const float*)d_in[2];
  const float* cb_bot = (const float*)d_in[3];
  float* out = (float*)d_out;
  char* ws = (char*)d_ws;

  short* ws_cb    = (short*)ws;                          // 2 MiB
  float* e2       = (float*)(ws + (2u<<20));             // 8 KiB
  int*   counts   = (int*)  (ws + (2u<<20) + 8192);      // 8 KiB
  float* loss_acc = (float*)(ws + (2u<<20) + 16384);     // 64 B
  int*   idx_all  = (int*)  (ws + (2u<<20) + 32768);     // 256 KiB

  short* ws_h = (short*)out;        // 64 MiB scratch == z region, rewritten by k4

  vq_prep   <<<512, 256, 0, stream>>>(cb_top, cb_bot, ws_cb, e2, counts, loss_acc);
  vq_prep_h <<<8192, 256, 0, stream>>>(h_top, h_bot, ws_h, loss_acc);
  vq_main   <<<dim3(256, 2), 256, 0, stream>>>(ws_cb, ws_h, e2, idx_all, counts, loss_acc);
  vq_zgather<<<1024, 256, 0, stream>>>(cb_top, cb_bot, idx_all, out);
  vq_final  <<<2, 1024, 0, stream>>>(counts, loss_acc, out + (size_t)2*NQ*DD);
}

// Round 9
// 281.451 us; speedup vs baseline: 2.3516x; 2.3516x over previous
//
#include <hip/hip_runtime.h>
#include <stdint.h>

#define TT 2048
#define DD 256
#define KK 1024
#define BB 16
#define NQ (BB*TT)   // 32768 queries per tensor

typedef __attribute__((ext_vector_type(8))) short short8;
typedef __attribute__((ext_vector_type(4))) short s16x4;
typedef __attribute__((ext_vector_type(4))) float f32x4;

#define AS1 __attribute__((address_space(1)))
#define AS3 __attribute__((address_space(3)))

__device__ __forceinline__ short bf16_rn(float x){
  unsigned u = __builtin_bit_cast(unsigned, x);
  unsigned r = u + 0x7fffu + ((u >> 16) & 1u);   // round-to-nearest-even
  return (short)(r >> 16);
}
__device__ __forceinline__ float bf16_to_f(short h){
  unsigned u = ((unsigned)(unsigned short)h) << 16;
  return __builtin_bit_cast(float, u);
}

// ---------------------------------------------------------------------------
// k1: codebook prep (verified): bf16 hi/lo split in the MFMA-A frag swizzle
// (per (ct,s) tile: 64 lanes x 16B contiguous), |e|^2, zero counts/loss.
// pos = ((ct*8+s)*64 + q*16 + c)*8 + j ; code k = ct*16+c.
// ---------------------------------------------------------------------------
__global__ void vq_prep(const float* __restrict__ cb_top,
                        const float* __restrict__ cb_bot,
                        short* __restrict__ ws_cb,
                        float* __restrict__ e2_all,
                        int* __restrict__ counts,
                        float* __restrict__ loss_acc){
  int gid = blockIdx.x*256 + threadIdx.x;          // 512 blocks = 2048 waves
  int wv = gid >> 6, lane = gid & 63;
  int t = wv >> 10, k = wv & 1023;
  const float* row = (t ? cb_bot : cb_top) + (size_t)k*DD;
  f32x4 v = *(const f32x4*)(row + lane*4);
  float s2 = v[0]*v[0] + v[1]*v[1] + v[2]*v[2] + v[3]*v[3];
  #pragma unroll
  for (int off = 1; off < 64; off <<= 1) s2 += __shfl_xor(s2, off, 64);
  if (lane == 0) e2_all[t*KK + k] = s2;

  s16x4 hi4, lo4;
  #pragma unroll
  for (int e = 0; e < 4; ++e){
    short hi = bf16_rn(v[e]);
    hi4[e] = hi;
    lo4[e] = bf16_rn(v[e] - bf16_to_f(hi));
  }
  int d0 = lane*4;
  int ct = k >> 4, c = k & 15, s = d0 >> 5, q = (d0 >> 3) & 3, j = d0 & 7;
  size_t pos = ((size_t)(ct*8 + s)*64 + q*16 + c)*8 + j;
  short* hib = ws_cb + (size_t)t * (2*KK*DD);
  *(s16x4*)(hib + pos) = hi4;
  *(s16x4*)(hib + (size_t)KK*DD + pos) = lo4;

  if (gid < 2*KK) counts[gid] = 0;
  if (gid < 2)    loss_acc[gid] = 0.f;
}

// ---------------------------------------------------------------------------
// k2: h prep — ATOMIC-FREE (r8's 421us was 32K same-address atomicAdds on
// loss_acc serializing in L2 at ~40cyc each; Guideline-12 violation).
// Per-block LDS reduce -> ONE plain store to partials[block]; vq_final sums.
// Each thread handles 2 s-units (16 loads in flight, 2x MLP of r8).
// Layout (unchanged, bitwise-identical split): plane offset
// ((qt*8+s)*64+lane)*8+j holds X[d=s*32+(lane>>4)*8+j][q=qt*16+(lane&15)].
// ws_h lives in d_out (overwritten later by vq_zgather).
// ---------------------------------------------------------------------------
__global__ void vq_prep_h(const float* __restrict__ h_top,
                          const float* __restrict__ h_bot,
                          short* __restrict__ ws_h,
                          float* __restrict__ partials){
  int gid = blockIdx.x*256 + threadIdx.x;          // 4096 blocks = 1M threads
  int tz = gid >> 19;
  int rem = gid & ((1<<19)-1);
  int qt = rem >> 8;                               // 0..2047
  int s2 = (rem >> 6) & 3;                         // s-pair
  int lane = rem & 63;
  int q = qt*16 + (lane & 15);
  int b = q >> 11, ti = q & (TT-1);
  const float* hbase = (tz ? h_bot : h_top) + (size_t)b*DD*TT + ti;
  float x2p = 0.f;
  #pragma unroll
  for (int sh = 0; sh < 2; ++sh){
    const int s = s2*2 + sh;
    const int d0 = s*32 + (lane>>4)*8;
    const float* hp = hbase + (size_t)d0*TT;
    short8 h8, l8;
    #pragma unroll
    for (int j = 0; j < 8; ++j){
      float v = hp[(size_t)j*TT];
      x2p += v*v;
      short hi = bf16_rn(v);
      h8[j] = hi;
      l8[j] = bf16_rn(v - bf16_to_f(hi));
    }
    short* dst = ws_h + (size_t)tz*(2*(size_t)NQ*DD)
               + ((size_t)(qt*8+s)*64 + lane)*8;
    *(short8*)dst = h8;
    *(short8*)(dst + (size_t)NQ*DD) = l8;
  }
  #pragma unroll
  for (int o = 1; o < 64; o <<= 1) x2p += __shfl_xor(x2p, o, 64);
  __shared__ float wred[4];
  const int w = threadIdx.x >> 6;
  if ((threadIdx.x & 63) == 0) wred[w] = x2p;
  __syncthreads();
  if (threadIdx.x == 0)
    partials[blockIdx.x] = wred[0] + wred[1] + wred[2] + wred[3];
}

// ---------------------------------------------------------------------------
// k3: tiled GEMM argmin (unchanged from r8). grid (256,2) = 512 WGs (2/CU),
// block 256 = 4 waves. WG tile 128 codes x 128 queries; wave 64x64; 64 iters
// of {stage A16KB+B16KB, 16 ds_read_b128, 48 MFMA into 16 indep chains}.
// ---------------------------------------------------------------------------
__global__ __launch_bounds__(256, 1) void vq_main(
    const short* __restrict__ ws_cb, const short* __restrict__ ws_h,
    const float* __restrict__ e2_all,
    int* __restrict__ idx_all, int* __restrict__ counts,
    float* __restrict__ loss_acc)
{
  const int tz = blockIdx.y;
  const short* cbA = ws_cb + (size_t)tz*(2*KK*DD);           // hi; lo at +KK*DD
  const short* hB  = ws_h  + (size_t)tz*(2*(size_t)NQ*DD);   // hi; lo at +NQ*DD
  const float* e2  = e2_all + tz*KK;

  const int tid = threadIdx.x;
  const int w = tid >> 6, lane = tid & 63;
  const int wm = w >> 1, wn = w & 1;
  const int q0 = blockIdx.x*128;
  const int qt0 = q0 >> 4;

  __shared__ short aL[2][2][8][512];   // [buf][hl][ct_l][lane*8+j]  32 KiB
  __shared__ short bL[2][2][8][512];   // [buf][hl][qt_l][lane*8+j]  32 KiB
  __shared__ float e2s[KK];            // 4 KiB
  __shared__ float smv[128];
  __shared__ int   smi[128];           // 69 KiB total

  *(f32x4*)(e2s + tid*4) = *(const f32x4*)(e2 + tid*4);

  auto stage = [&](int buf, int it){
    const int mt = it >> 3, ks = it & 7;
    short* aBase = &aL[buf][0][0][0];
    short* bBase = &bL[buf][0][0][0];
    #pragma unroll
    for (int k2 = 0; k2 < 8; ++k2){
      int u = w*8 + k2;
      if (u < 16){
        int hl = u & 1, ct_l = u >> 1;
        const short* src = cbA + (size_t)hl*(KK*DD)
                         + (size_t)((mt*8 + ct_l)*8 + ks)*512 + lane*8;
        short* dst = aBase + (hl*8 + ct_l)*512 + lane*8;
        __builtin_amdgcn_global_load_lds((AS1 void*)src, (AS3 void*)dst, 16, 0, 0);
      } else {
        int v2 = u - 16, hl = v2 & 1, qt_l = v2 >> 1;
        const short* src = hB + (size_t)hl*((size_t)NQ*DD)
                         + (size_t)((qt0 + qt_l)*8 + ks)*512 + lane*8;
        short* dst = bBase + (hl*8 + qt_l)*512 + lane*8;
        __builtin_amdgcn_global_load_lds((AS1 void*)src, (AS3 void*)dst, 16, 0, 0);
      }
    }
  };

  stage(0, 0);

  f32x4 acc[4][4];
  #pragma unroll
  for (int am = 0; am < 4; ++am)
    #pragma unroll
    for (int bn = 0; bn < 4; ++bn)
      acc[am][bn] = (f32x4){0.f,0.f,0.f,0.f};

  float best[4] = {3.4e38f, 3.4e38f, 3.4e38f, 3.4e38f};
  int   bidx[4] = {0,0,0,0};

  for (int it = 0; it < 64; ++it){
    const int buf = it & 1;
    const int mt = it >> 3, ks = it & 7;
    __syncthreads();                              // stage(it) landed; buf^1 free
    if (it + 1 < 64) stage(buf ^ 1, it + 1);
    __builtin_amdgcn_sched_barrier(0);            // stage issues before reads

    short8 ah[4], al4[4], bh[4], bl4[4];
    #pragma unroll
    for (int am = 0; am < 4; ++am){
      ah[am]  = *(const short8*)(&aL[buf][0][wm*4+am][lane*8]);
      al4[am] = *(const short8*)(&aL[buf][1][wm*4+am][lane*8]);
    }
    #pragma unroll
    for (int bn = 0; bn < 4; ++bn){
      bh[bn]  = *(const short8*)(&bL[buf][0][wn*4+bn][lane*8]);
      bl4[bn] = *(const short8*)(&bL[buf][1][wn*4+bn][lane*8]);
    }
    __builtin_amdgcn_s_setprio(1);
    #pragma unroll
    for (int am = 0; am < 4; ++am)
      #pragma unroll
      for (int bn = 0; bn < 4; ++bn){
        acc[am][bn] = __builtin_amdgcn_mfma_f32_16x16x32_bf16(ah[am],  bh[bn],  acc[am][bn], 0,0,0);
        acc[am][bn] = __builtin_amdgcn_mfma_f32_16x16x32_bf16(ah[am],  bl4[bn], acc[am][bn], 0,0,0);
        acc[am][bn] = __builtin_amdgcn_mfma_f32_16x16x32_bf16(al4[am], bh[bn],  acc[am][bn], 0,0,0);
      }
    __builtin_amdgcn_s_setprio(0);

    if (ks == 7){                                 // M-tile argmin + acc reset
      const int g4 = lane >> 4;
      #pragma unroll
      for (int am = 0; am < 4; ++am){
        const int code0 = mt*128 + wm*64 + am*16 + g4*4;
        const f32x4 e2v = *(const f32x4*)(e2s + code0);
        #pragma unroll
        for (int bn = 0; bn < 4; ++bn){
          #pragma unroll
          for (int r = 0; r < 4; ++r){
            float sv = e2v[r] - 2.0f*acc[am][bn][r];
            if (sv < best[bn]){ best[bn] = sv; bidx[bn] = code0 + r; }
          }
          acc[am][bn] = (f32x4){0.f,0.f,0.f,0.f};
        }
      }
    }
  }

  #pragma unroll
  for (int o = 16; o <= 32; o <<= 1){
    #pragma unroll
    for (int bn = 0; bn < 4; ++bn){
      float ov = __shfl_xor(best[bn], o, 64);
      int   oi = __shfl_xor(bidx[bn], o, 64);
      if (ov < best[bn] || (ov == best[bn] && oi < bidx[bn])){ best[bn] = ov; bidx[bn] = oi; }
    }
  }

  const int g4 = lane >> 4;
  float bv = (g4 == 0) ? best[0] : (g4 == 1) ? best[1] : (g4 == 2) ? best[2] : best[3];
  int   bi = (g4 == 0) ? bidx[0] : (g4 == 1) ? bidx[1] : (g4 == 2) ? bidx[2] : bidx[3];

  __syncthreads();
  if (wm == 1){ smv[wn*64 + lane] = bv; smi[wn*64 + lane] = bi; }
  __syncthreads();
  if (wm == 0){
    float ov = smv[wn*64 + lane]; int oi = smi[wn*64 + lane];
    if (ov < bv || (ov == bv && oi < bi)){ bv = ov; bi = oi; }
    idx_all[tz*NQ + q0 + wn*64 + lane] = bi;
    atomicAdd(&counts[tz*KK + bi], 1);
    float ld = bv;                                 // Sum|x|^2 via partials (k2)
    #pragma unroll
    for (int o = 1; o < 64; o <<= 1) ld += __shfl_xor(ld, o, 64);
    if (lane == 0) atomicAdd(&loss_acc[tz], ld);   // 512 atomics total: fine
  }
}

// ---------------------------------------------------------------------------
// k4: z gather (unchanged). Overwrites the ws_h scratch region of d_out.
// ---------------------------------------------------------------------------
__global__ void vq_zgather(const float* __restrict__ cb_top,
                           const float* __restrict__ cb_bot,
                           const int* __restrict__ idx_all,
                           float* __restrict__ out){
  int gid = blockIdx.x*256 + threadIdx.x;          // 1024 blocks = 262144 thr
  int tz = gid >> 17;
  int rem = gid & ((1<<17)-1);
  int quarter = rem >> 15;
  int q = rem & (NQ-1);
  int b = q >> 11, ti = q & (TT-1);
  int idx = idx_all[tz*NQ + q];
  const float* crow = (tz ? cb_bot : cb_top) + (size_t)idx*DD + quarter*64;
  float* zb = out + (size_t)tz*((size_t)NQ*DD) + (size_t)(b*DD + quarter*64)*TT + ti;
  #pragma unroll
  for (int d = 0; d < 64; d += 4){
    f32x4 cv = *(const f32x4*)(crow + d);
    zb[(size_t)(d+0)*TT] = cv[0];
    zb[(size_t)(d+1)*TT] = cv[1];
    zb[(size_t)(d+2)*TT] = cv[2];
    zb[(size_t)(d+3)*TT] = cv[3];
  }
}

// ---------------------------------------------------------------------------
// k5: perplexities + loss scalars (now also reduces the x2 partials).
// outs = d_out + 2*NQ*DD.
// ---------------------------------------------------------------------------
__global__ void vq_final(const int* __restrict__ counts,
                         const float* __restrict__ loss_acc,
                         const float* __restrict__ partials,
                         float* __restrict__ outs){
  __shared__ float red[1024];
  const int tid = threadIdx.x;
  const int t = blockIdx.x;
  float p = (float)counts[t*KK + tid] * (1.0f/(float)NQ);
  red[tid] = p * logf(p + 1e-10f);
  __syncthreads();
  for (int s = 512; s > 0; s >>= 1){
    if (tid < s) red[tid] += red[tid + s];
    __syncthreads();
  }
  if (tid == 0) outs[2 + t] = expf(-red[0]);
  __syncthreads();
  if (t == 0){
    red[tid] = partials[tid] + partials[tid + 1024]
             + partials[tid + 2048] + partials[tid + 3072];
    __syncthreads();
    for (int s = 512; s > 0; s >>= 1){
      if (tid < s) red[tid] += red[tid + s];
      __syncthreads();
    }
    if (tid == 0){
      float l = (loss_acc[0] + loss_acc[1] + red[0]) * (1.0f/8388608.0f);
      outs[0] = l;   // vq_loss
      outs[1] = l;   // commitment_loss (same forward value)
    }
  }
}

extern "C" void kernel_launch(void* const* d_in, const int* in_sizes, int n_in,
                              void* d_out, int out_size, void* d_ws, size_t ws_size,
                              hipStream_t stream)
{
  (void)in_sizes; (void)n_in; (void)out_size; (void)ws_size;
  const float* h_top  = (const float*)d_in[0];
  const float* h_bot  = (const float*)d_in[1];
  const float* cb_top = (const float*)d_in[2];
  const float* cb_bot = (const float*)d_in[3];
  float* out = (float*)d_out;
  char* ws = (char*)d_ws;

  short* ws_cb    = (short*)ws;                          // 2 MiB
  float* e2       = (float*)(ws + (2u<<20));             // 8 KiB
  int*   counts   = (int*)  (ws + (2u<<20) + 8192);      // 8 KiB
  float* loss_acc = (float*)(ws + (2u<<20) + 16384);     // 64 B
  int*   idx_all  = (int*)  (ws + (2u<<20) + 32768);     // 256 KiB
  float* partials = (float*)(ws + (2u<<20) + 32768 + 262144);  // 16 KiB

  short* ws_h = (short*)out;        // 64 MiB scratch == z region, rewritten by k4

  vq_prep   <<<512, 256, 0, stream>>>(cb_top, cb_bot, ws_cb, e2, counts, loss_acc);
  vq_prep_h <<<4096, 256, 0, stream>>>(h_top, h_bot, ws_h, partials);
  vq_main   <<<dim3(256, 2), 256, 0, stream>>>(ws_cb, ws_h, e2, idx_all, counts, loss_acc);
  vq_zgather<<<1024, 256, 0, stream>>>(cb_top, cb_bot, idx_all, out);
  vq_final  <<<2, 1024, 0, stream>>>(counts, loss_acc, partials, out + (size_t)2*NQ*DD);
}